// Round 2
// baseline (828.380 us; speedup 1.0000x reference)
//
#include <hip/hip_runtime.h>
#include <hip/hip_bf16.h>

typedef unsigned short u16;
typedef unsigned long long u64;
typedef __attribute__((ext_vector_type(4))) float f32x4;
typedef __attribute__((ext_vector_type(8))) short s16x8;

constexpr int Sdim = 1024;
constexpr int Hh   = 8;
constexpr int DKc  = 96;
constexpr int Dd   = 768;
constexpr int Bb   = 16;

static __device__ __forceinline__ u16 f2bf(float f) {
    unsigned u = __builtin_bit_cast(unsigned, f);
    u += 0x7fff + ((u >> 16) & 1);   // round-to-nearest-even
    return (u16)(u >> 16);
}

// ---------------------------------------------------------------------------
// Kernel 1: convert the 4 weight matrices (768x768 fp32) to bf16
// grid (576, 4), block 256; 576*256*4 = 589824 elems per weight
// ---------------------------------------------------------------------------
__global__ __launch_bounds__(256) void convw_kernel(
    const float* w0, const float* w1, const float* w2, const float* w3, u16* dst)
{
    const float* src = (blockIdx.y == 0) ? w0 : (blockIdx.y == 1) ? w1
                      : (blockIdx.y == 2) ? w2 : w3;
    u16* d = dst + (size_t)blockIdx.y * 589824;
    int i = (blockIdx.x * 256 + threadIdx.x) * 4;
    float4 v = *(const float4*)(src + i);
    ushort4 o;
    o.x = f2bf(v.x); o.y = f2bf(v.y); o.z = f2bf(v.z); o.w = f2bf(v.w);
    *(ushort4*)(d + i) = o;
}

// ---------------------------------------------------------------------------
// Kernel 1b: bit-pack the mask. [B,4,S,S] int32 -> u32 bitfield (8 MiB).
// bit b of packed[w] == (mask[w*32 + b] != 0). Wave-wide ballot, coalesced.
// ---------------------------------------------------------------------------
__global__ __launch_bounds__(256) void maskpack_kernel(const int* mask, unsigned* packed)
{
    const size_t total  = (size_t)Bb * 4 * Sdim * Sdim;   // 67108864
    const size_t stride = (size_t)gridDim.x * 256;
    const int lane = threadIdx.x & 63;
    for (size_t i = (size_t)blockIdx.x * 256 + threadIdx.x; i < total; i += stride) {
        int mv = mask[i];
        u64 bal = __ballot(mv != 0);
        size_t w0 = (i - lane) >> 5;      // u32 index of this wave's span
        if (lane == 0)  packed[w0]     = (unsigned)bal;
        if (lane == 32) packed[w0 + 1] = (unsigned)(bal >> 32);
    }
}

// ---------------------------------------------------------------------------
// Kernel 2/4: GEMM  out = A @ W^T + bias
//   A: [M,K] (fp32 when QKV, bf16 when final), W: bf16 [N,K] (K-major = B^T)
//   QKV: grid (6,128,3); z=0 -> Q [B,H,S,DK], z=1 -> K [B,H,S,DK],
//        z=2 -> V^T [B,H,DK,S]; final: grid (6,128,1) fp32 out [M,N]
//   Tile 128x128, BK=64, 4 waves (2x2), 16x16x32 bf16 MFMA
// ---------------------------------------------------------------------------
template<bool QKV>
__global__ __launch_bounds__(256) void gemm_kernel(
    const float* q_f32, const float* k_f32, const float* v_f32,
    const u16* xb, const u16* wb,
    const float* bq, const float* bk, const float* bv, const float* bo,
    u16* qb, u16* kb, u16* vtb, float* out, int Ktot)
{
    constexpr int LDT = 72;                       // 64 + 8 pad (144B rows, 16B aligned)
    __shared__ u16 As[128][LDT];
    __shared__ u16 Bs[128][LDT];

    const int z = QKV ? (int)blockIdx.z : 3;
    const float* Af = QKV ? (z == 0 ? q_f32 : z == 1 ? k_f32 : v_f32) : nullptr;
    const u16*   Ab = QKV ? nullptr : xb;
    const u16*   W  = wb + (size_t)(QKV ? z : 3) * 589824;
    const float* bias = QKV ? (z == 0 ? bq : z == 1 ? bk : bv) : bo;

    const int tid = threadIdx.x;
    const int lane = tid & 63;
    const int w = tid >> 6;
    const int wr = (w >> 1) * 64, wc = (w & 1) * 64;
    const int m0 = blockIdx.y * 128, n0 = blockIdx.x * 128;

    f32x4 acc[4][4] = {};

    for (int k0 = 0; k0 < Ktot; k0 += 64) {
        __syncthreads();
        // ---- stage A tile (128 x 64) ----
        if constexpr (QKV) {
            // fp32 source: 128 rows x 64 f32 = 2048 16B-chunks, 8 per thread
            #pragma unroll
            for (int i = 0; i < 8; i++) {
                int c = tid + i * 256;
                int row = c >> 4, o4 = (c & 15) * 4;
                float4 v = *(const float4*)(Af + (size_t)(m0 + row) * Ktot + k0 + o4);
                ushort4 o;
                o.x = f2bf(v.x); o.y = f2bf(v.y); o.z = f2bf(v.z); o.w = f2bf(v.w);
                *(ushort4*)&As[row][o4] = o;
            }
        } else {
            // bf16 source: 1024 16B-chunks, 4 per thread
            #pragma unroll
            for (int i = 0; i < 4; i++) {
                int c = tid + i * 256;
                int row = c >> 3, o8 = (c & 7) * 8;
                *(int4*)&As[row][o8] =
                    *(const int4*)(Ab + (size_t)(m0 + row) * Ktot + k0 + o8);
            }
        }
        // ---- stage B tile (weights, bf16 [N][K]) ----
        #pragma unroll
        for (int i = 0; i < 4; i++) {
            int c = tid + i * 256;
            int row = c >> 3, o8 = (c & 7) * 8;
            *(int4*)&Bs[row][o8] =
                *(const int4*)(W + (size_t)(n0 + row) * Ktot + k0 + o8);
        }
        __syncthreads();
        // ---- compute ----
        #pragma unroll
        for (int kk = 0; kk < 2; kk++) {
            s16x8 a[4], b[4];
            #pragma unroll
            for (int mi = 0; mi < 4; mi++)
                a[mi] = *(const s16x8*)&As[wr + mi * 16 + (lane & 15)][kk * 32 + (lane >> 4) * 8];
            #pragma unroll
            for (int ni = 0; ni < 4; ni++)
                b[ni] = *(const s16x8*)&Bs[wc + ni * 16 + (lane & 15)][kk * 32 + (lane >> 4) * 8];
            #pragma unroll
            for (int mi = 0; mi < 4; mi++)
                #pragma unroll
                for (int ni = 0; ni < 4; ni++)
                    acc[mi][ni] = __builtin_amdgcn_mfma_f32_16x16x32_bf16(
                        a[mi], b[ni], acc[mi][ni], 0, 0, 0);
        }
    }

    // ---- epilogue ----
    #pragma unroll
    for (int mi = 0; mi < 4; mi++) {
        #pragma unroll
        for (int ni = 0; ni < 4; ni++) {
            int nc = n0 + wc + ni * 16 + (lane & 15);
            int mr0 = m0 + wr + mi * 16 + (lane >> 4) * 4;
            float bvv = bias[nc];
            float vals[4];
            #pragma unroll
            for (int r = 0; r < 4; r++) vals[r] = acc[mi][ni][r] + bvv;

            if constexpr (!QKV) {
                #pragma unroll
                for (int r = 0; r < 4; r++)
                    out[(size_t)(mr0 + r) * Dd + nc] = vals[r];
            } else {
                int b_ = mr0 >> 10, s_ = mr0 & 1023;   // r=0..3 stays in-batch (4-aligned)
                int h_ = nc / DKc, dk = nc - h_ * DKc;
                if (z == 2) {
                    ushort4 o;
                    o.x = f2bf(vals[0]); o.y = f2bf(vals[1]);
                    o.z = f2bf(vals[2]); o.w = f2bf(vals[3]);
                    *(ushort4*)&vtb[((size_t)(b_ * Hh + h_) * DKc + dk) * Sdim + s_] = o;
                } else {
                    u16* dst = (z == 0) ? qb : kb;
                    #pragma unroll
                    for (int r = 0; r < 4; r++)
                        dst[((size_t)(b_ * Hh + h_) * Sdim + (s_ + r)) * DKc + dk] = f2bf(vals[r]);
                }
            }
        }
    }
}

// ---------------------------------------------------------------------------
// Kernel 3: flash attention. grid (S/64=16, B*H=128), block 256 (4 waves)
//   Each WG: 64 q-rows of one (b,h). Wave w owns q-rows [w*16, w*16+16).
//   K-tiles of 64 keys; online softmax; PV via P staged through LDS.
//   Mask comes from the 8 MiB packed bitfield (L2/L3-resident).
// ---------------------------------------------------------------------------
__global__ __launch_bounds__(256) void attn_kernel(
    const u16* qb, const u16* kb, const u16* vtb, const unsigned* mpacked, u16* xb)
{
    __shared__ u16 kbuf[64][104];    // K tile [key][d], also Q staging; 2-way-free pad
    __shared__ u16 vbuf[96][72];     // V^T tile [d'][key]
    __shared__ u16 pbuf[4][16][72];  // per-wave P [qrow][key]

    const int tid = threadIdx.x;
    const int lane = tid & 63;
    const int w = tid >> 6;
    const int bh = blockIdx.y;
    const int b_ = bh >> 3, h_ = bh & 7, g_ = h_ & 3;
    const int q0 = blockIdx.x * 64;

    const u16* Qp = qb + (size_t)bh * Sdim * DKc;
    const u16* Kp = kb + (size_t)bh * Sdim * DKc;
    const u16* Vp = vtb + (size_t)bh * DKc * Sdim;
    const unsigned* Pm = mpacked + (((size_t)(b_ * 4 + g_) * Sdim * Sdim) >> 5);

    // stage Q tile (64 x 96) into kbuf, pull A-frags to registers
    #pragma unroll
    for (int i = 0; i < 3; i++) {
        int c = tid + i * 256;
        int row = c / 12, o = (c % 12) * 8;
        *(int4*)&kbuf[row][o] = *(const int4*)(Qp + (size_t)(q0 + row) * DKc + o);
    }
    __syncthreads();
    s16x8 qf[3];
    #pragma unroll
    for (int kk = 0; kk < 3; kk++)
        qf[kk] = *(const s16x8*)&kbuf[w * 16 + (lane & 15)][kk * 32 + (lane >> 4) * 8];
    __syncthreads();

    float m_run[4], l_run[4];
    f32x4 acc[6];
    #pragma unroll
    for (int r = 0; r < 4; r++) { m_run[r] = -1e30f; l_run[r] = 0.f; }
    #pragma unroll
    for (int n2 = 0; n2 < 6; n2++) acc[n2] = (f32x4){0.f, 0.f, 0.f, 0.f};

    const float sc = 0.10206207261596575f;  // 1/sqrt(96)
    const int qrow = q0 + w * 16 + (lane >> 4) * 4;

    for (int kt = 0; kt < 16; kt++) {
        const int kb0 = kt * 64;
        __syncthreads();
        // stage K tile [64][96]
        #pragma unroll
        for (int i = 0; i < 3; i++) {
            int c = tid + i * 256;
            int row = c / 12, o = (c % 12) * 8;
            *(int4*)&kbuf[row][o] = *(const int4*)(Kp + (size_t)(kb0 + row) * DKc + o);
        }
        // stage V^T tile [96][64]
        #pragma unroll
        for (int i = 0; i < 3; i++) {
            int c = tid + i * 256;
            int row = c >> 3, o = (c & 7) * 8;
            *(int4*)&vbuf[row][o] = *(const int4*)(Vp + (size_t)row * Sdim + kb0 + o);
        }
        __syncthreads();

        // ---- QK^T ----
        float s[4][4];  // [ni][r]
        #pragma unroll
        for (int ni = 0; ni < 4; ni++) {
            f32x4 c4 = {0.f, 0.f, 0.f, 0.f};
            #pragma unroll
            for (int kk = 0; kk < 3; kk++) {
                s16x8 bfr = *(const s16x8*)&kbuf[ni * 16 + (lane & 15)][kk * 32 + (lane >> 4) * 8];
                c4 = __builtin_amdgcn_mfma_f32_16x16x32_bf16(qf[kk], bfr, c4, 0, 0, 0);
            }
            #pragma unroll
            for (int r = 0; r < 4; r++) s[ni][r] = c4[r] * sc;
        }

        // ---- mask (broadcast u64 per q-row covering this 64-key tile) ----
        #pragma unroll
        for (int r = 0; r < 4; r++) {
            u64 mbits = *(const u64*)(Pm + (((size_t)(qrow + r) * Sdim + kb0) >> 5));
            #pragma unroll
            for (int ni = 0; ni < 4; ni++)
                if (!((mbits >> (ni * 16 + (lane & 15))) & 1)) s[ni][r] = -1e9f;
        }

        // ---- online softmax (rows live across 16 lanes of each 4-lane-group set) ----
        float alpha[4];
        #pragma unroll
        for (int r = 0; r < 4; r++) {
            float tmax = fmaxf(fmaxf(s[0][r], s[1][r]), fmaxf(s[2][r], s[3][r]));
            tmax = fmaxf(tmax, __shfl_xor(tmax, 1));
            tmax = fmaxf(tmax, __shfl_xor(tmax, 2));
            tmax = fmaxf(tmax, __shfl_xor(tmax, 4));
            tmax = fmaxf(tmax, __shfl_xor(tmax, 8));
            float mn = fmaxf(m_run[r], tmax);
            alpha[r] = __expf(m_run[r] - mn);
            m_run[r] = mn;
            float ps = 0.f;
            #pragma unroll
            for (int ni = 0; ni < 4; ni++) {
                float p = __expf(s[ni][r] - mn);
                s[ni][r] = p;
                ps += p;
            }
            ps += __shfl_xor(ps, 1);
            ps += __shfl_xor(ps, 2);
            ps += __shfl_xor(ps, 4);
            ps += __shfl_xor(ps, 8);
            l_run[r] = l_run[r] * alpha[r] + ps;
        }

        // ---- write P (C-layout -> LDS), rescale acc ----
        #pragma unroll
        for (int ni = 0; ni < 4; ni++)
            #pragma unroll
            for (int r = 0; r < 4; r++)
                pbuf[w][(lane >> 4) * 4 + r][ni * 16 + (lane & 15)] = f2bf(s[ni][r]);
        #pragma unroll
        for (int n2 = 0; n2 < 6; n2++)
            #pragma unroll
            for (int r = 0; r < 4; r++) acc[n2][r] *= alpha[r];
        asm volatile("s_waitcnt lgkmcnt(0)" ::: "memory");  // wave-private P write->read

        // ---- PV ----
        #pragma unroll
        for (int kk = 0; kk < 2; kk++) {
            s16x8 pf = *(const s16x8*)&pbuf[w][lane & 15][kk * 32 + (lane >> 4) * 8];
            #pragma unroll
            for (int n2 = 0; n2 < 6; n2++) {
                s16x8 vf = *(const s16x8*)&vbuf[n2 * 16 + (lane & 15)][kk * 32 + (lane >> 4) * 8];
                acc[n2] = __builtin_amdgcn_mfma_f32_16x16x32_bf16(pf, vf, acc[n2], 0, 0, 0);
            }
        }
    }

    // ---- epilogue: xb[b, s, h*96 + d'] bf16 ----
    #pragma unroll
    for (int n2 = 0; n2 < 6; n2++) {
        int dc = h_ * DKc + n2 * 16 + (lane & 15);
        #pragma unroll
        for (int r = 0; r < 4; r++) {
            float val = acc[n2][r] / l_run[r];
            xb[((size_t)(b_ * Sdim) + (qrow + r)) * Dd + dc] = f2bf(val);
        }
    }
}

// ---------------------------------------------------------------------------
extern "C" void kernel_launch(void* const* d_in, const int* in_sizes, int n_in,
                              void* d_out, int out_size, void* d_ws, size_t ws_size,
                              hipStream_t stream)
{
    const float* query = (const float*)d_in[0];
    const float* key   = (const float*)d_in[1];
    const float* value = (const float*)d_in[2];
    const int*   mask  = (const int*)d_in[3];
    const float* Wq = (const float*)d_in[4];
    const float* bq = (const float*)d_in[5];
    const float* Wk = (const float*)d_in[6];
    const float* bk = (const float*)d_in[7];
    const float* Wv = (const float*)d_in[8];
    const float* bv = (const float*)d_in[9];
    const float* Wo = (const float*)d_in[10];
    const float* bo = (const float*)d_in[11];
    float* out = (float*)d_out;

    char* ws = (char*)d_ws;
    u16* qb   = (u16*)(ws);                 // 25165824 B  [B,H,S,DK] bf16
    u16* kb   = (u16*)(ws + 25165824);      // 25165824 B
    u16* vtb  = (u16*)(ws + 50331648);      // 25165824 B  [B,H,DK,S] bf16
    u16* xb   = (u16*)(ws + 75497472);      // 25165824 B  [B,S,D] bf16
    u16* wb   = (u16*)(ws + 100663296);     //  4718592 B  4x [768,768] bf16
    unsigned* mp = (unsigned*)(ws + 105381888); // 8388608 B packed mask

    convw_kernel<<<dim3(576, 4), 256, 0, stream>>>(Wq, Wk, Wv, Wo, wb);
    maskpack_kernel<<<dim3(2048), 256, 0, stream>>>(mask, mp);
    gemm_kernel<true><<<dim3(6, 128, 3), 256, 0, stream>>>(
        query, key, value, nullptr, wb, bq, bk, bv, bo, qb, kb, vtb, out, Dd);
    attn_kernel<<<dim3(16, 128), 256, 0, stream>>>(qb, kb, vtb, mp, xb);
    gemm_kernel<false><<<dim3(6, 128, 1), 256, 0, stream>>>(
        nullptr, nullptr, nullptr, xb, wb, bq, bk, bv, bo, qb, kb, vtb, out, Dd);
}

// Round 4
// 810.905 us; speedup vs baseline: 1.0215x; 1.0215x over previous
//
#include <hip/hip_runtime.h>
#include <hip/hip_bf16.h>

typedef unsigned short u16;
typedef unsigned int u32;
typedef unsigned long long u64;
typedef __attribute__((ext_vector_type(4))) float f32x4;
typedef __attribute__((ext_vector_type(8))) short s16x8;

constexpr int Sdim = 1024;
constexpr int Hh   = 8;
constexpr int DKc  = 96;
constexpr int Dd   = 768;
constexpr int Bb   = 16;

static __device__ __forceinline__ u16 f2bf(float f) {
    unsigned u = __builtin_bit_cast(unsigned, f);
    u += 0x7fff + ((u >> 16) & 1);   // round-to-nearest-even
    return (u16)(u >> 16);
}

// async global->LDS, 16B per lane; LDS dest must be wave-uniform base (HW adds lane*16)
static __device__ __forceinline__ void gload_lds16(const u16* g, u16* l) {
    __builtin_amdgcn_global_load_lds(
        (const __attribute__((address_space(1))) u32*)g,
        (__attribute__((address_space(3))) u32*)l, 16, 0, 0);
}

// ---------------------------------------------------------------------------
// Kernel 1: convert the 4 weight matrices (768x768 fp32) to bf16
// ---------------------------------------------------------------------------
__global__ __launch_bounds__(256) void convw_kernel(
    const float* w0, const float* w1, const float* w2, const float* w3, u16* dst)
{
    const float* src = (blockIdx.y == 0) ? w0 : (blockIdx.y == 1) ? w1
                      : (blockIdx.y == 2) ? w2 : w3;
    u16* d = dst + (size_t)blockIdx.y * 589824;
    int i = (blockIdx.x * 256 + threadIdx.x) * 4;
    float4 v = *(const float4*)(src + i);
    ushort4 o;
    o.x = f2bf(v.x); o.y = f2bf(v.y); o.z = f2bf(v.z); o.w = f2bf(v.w);
    *(ushort4*)(d + i) = o;
}

// ---------------------------------------------------------------------------
// Kernel 1b: bit-pack the mask. [B,4,S,S] int32 -> u32 bitfield (8 MiB).
// ---------------------------------------------------------------------------
__global__ __launch_bounds__(256) void maskpack_kernel(const int* mask, unsigned* packed)
{
    const size_t total  = (size_t)Bb * 4 * Sdim * Sdim;   // 67108864
    const size_t stride = (size_t)gridDim.x * 256;
    const int lane = threadIdx.x & 63;
    for (size_t i = (size_t)blockIdx.x * 256 + threadIdx.x; i < total; i += stride) {
        int mv = mask[i];
        u64 bal = __ballot(mv != 0);
        size_t w0 = (i - lane) >> 5;      // u32 index of this wave's span
        if (lane == 0)  packed[w0]     = (unsigned)bal;
        if (lane == 32) packed[w0 + 1] = (unsigned)(bal >> 32);
    }
}

// ---------------------------------------------------------------------------
// Kernel 2/4: GEMM  out = A @ W^T + bias
//   B (weights) staged via global_load_lds width=16 into linear LDS (m97).
//   QKV: A = fp32 activations, reg-staged with convert (padded LDS tile).
//   !QKV: A = bf16 xb, also async; fp32 out + bias.
// ---------------------------------------------------------------------------
template<bool QKV>
__global__ __launch_bounds__(256) void gemm_kernel(
    const float* q_f32, const float* k_f32, const float* v_f32,
    const u16* xb, const u16* wb,
    const float* bq, const float* bk, const float* bv, const float* bo,
    u16* qb, u16* kb, u16* vtb, float* out, int Ktot)
{
    constexpr int LDA = QKV ? 72 : 64;            // pad only the reg-staged A tile
    __shared__ u16 As[128][LDA];
    __shared__ u16 Bs[128][64];

    const int z = QKV ? (int)blockIdx.z : 3;
    const float* Af = QKV ? (z == 0 ? q_f32 : z == 1 ? k_f32 : v_f32) : nullptr;
    const u16*   Ab = QKV ? nullptr : xb;
    const u16*   W  = wb + (size_t)(QKV ? z : 3) * 589824;
    const float* bias = QKV ? (z == 0 ? bq : z == 1 ? bk : bv) : bo;

    const int tid = threadIdx.x;
    const int lane = tid & 63;
    const int w = tid >> 6;
    const int wr = (w >> 1) * 64, wc = (w & 1) * 64;
    const int m0 = blockIdx.y * 128, n0 = blockIdx.x * 128;

    f32x4 acc[4][4] = {};

    for (int k0 = 0; k0 < Ktot; k0 += 64) {
        __syncthreads();
        // ---- B tile async: 128x64 bf16 = 1024 16B-chunks, 16 wave-issues ----
        #pragma unroll
        for (int i = 0; i < 4; i++) {
            int c = (w * 4 + i) * 64 + lane;
            int row = c >> 3, col = (c & 7) * 8;
            gload_lds16(W + (size_t)(n0 + row) * Ktot + k0 + col,
                        ((u16*)Bs) + (size_t)(w * 4 + i) * 512);
        }
        // ---- A tile ----
        if constexpr (QKV) {
            // fp32 source: reg-stage + convert (overlaps with async B)
            #pragma unroll
            for (int i = 0; i < 8; i++) {
                int c = tid + i * 256;
                int row = c >> 4, o4 = (c & 15) * 4;
                float4 v = *(const float4*)(Af + (size_t)(m0 + row) * Ktot + k0 + o4);
                ushort4 o;
                o.x = f2bf(v.x); o.y = f2bf(v.y); o.z = f2bf(v.z); o.w = f2bf(v.w);
                *(ushort4*)&As[row][o4] = o;
            }
        } else {
            #pragma unroll
            for (int i = 0; i < 4; i++) {
                int c = (w * 4 + i) * 64 + lane;
                int row = c >> 3, col = (c & 7) * 8;
                gload_lds16(Ab + (size_t)(m0 + row) * Ktot + k0 + col,
                            ((u16*)As) + (size_t)(w * 4 + i) * 512);
            }
        }
        __syncthreads();   // drains vmcnt (incl. global_load_lds) + lgkm
        // ---- compute ----
        #pragma unroll
        for (int kk = 0; kk < 2; kk++) {
            s16x8 a[4], b[4];
            #pragma unroll
            for (int mi = 0; mi < 4; mi++)
                a[mi] = *(const s16x8*)&As[wr + mi * 16 + (lane & 15)][kk * 32 + (lane >> 4) * 8];
            #pragma unroll
            for (int ni = 0; ni < 4; ni++)
                b[ni] = *(const s16x8*)&Bs[wc + ni * 16 + (lane & 15)][kk * 32 + (lane >> 4) * 8];
            #pragma unroll
            for (int mi = 0; mi < 4; mi++)
                #pragma unroll
                for (int ni = 0; ni < 4; ni++)
                    acc[mi][ni] = __builtin_amdgcn_mfma_f32_16x16x32_bf16(
                        a[mi], b[ni], acc[mi][ni], 0, 0, 0);
        }
    }

    // ---- epilogue ----
    #pragma unroll
    for (int mi = 0; mi < 4; mi++) {
        #pragma unroll
        for (int ni = 0; ni < 4; ni++) {
            int nc = n0 + wc + ni * 16 + (lane & 15);
            int mr0 = m0 + wr + mi * 16 + (lane >> 4) * 4;
            float bvv = bias[nc];
            float vals[4];
            #pragma unroll
            for (int r = 0; r < 4; r++) vals[r] = acc[mi][ni][r] + bvv;

            if constexpr (!QKV) {
                #pragma unroll
                for (int r = 0; r < 4; r++)
                    out[(size_t)(mr0 + r) * Dd + nc] = vals[r];
            } else {
                int b_ = mr0 >> 10, s_ = mr0 & 1023;   // r=0..3 stays in-batch (4-aligned)
                int h_ = nc / DKc, dk = nc - h_ * DKc;
                if (z == 2) {
                    ushort4 o;
                    o.x = f2bf(vals[0]); o.y = f2bf(vals[1]);
                    o.z = f2bf(vals[2]); o.w = f2bf(vals[3]);
                    *(ushort4*)&vtb[((size_t)(b_ * Hh + h_) * DKc + dk) * Sdim + s_] = o;
                } else {
                    u16* dst = (z == 0) ? qb : kb;
                    #pragma unroll
                    for (int r = 0; r < 4; r++)
                        dst[((size_t)(b_ * Hh + h_) * Sdim + (s_ + r)) * DKc + dk] = f2bf(vals[r]);
                }
            }
        }
    }
}

// ---------------------------------------------------------------------------
// Kernel 3: flash attention, SWAPPED QK^T (S^T = K x Q^T) so each lane owns
// one q-row's 16 scores per 64-key tile: in-register reduce + 2 shfl_xor.
// exp2-domain softmax, defer-max (THR=8), P packed via v_cvt_pk_bf16_f32.
// grid (S/64=16, B*H=128), block 256 (4 waves, wave w: q-rows [w*16, w*16+16))
// ---------------------------------------------------------------------------
__global__ __launch_bounds__(256) void attn_kernel(
    const u16* qb, const u16* kb, const u16* vtb, const unsigned* mpacked, u16* xb)
{
    __shared__ u16 kbuf[64][104];    // K tile [key][d] (also Q staging); 2-way-free pad
    __shared__ u16 vbuf[96][72];     // V^T tile [d'][key]
    __shared__ u16 pbuf[4][16][72];  // per-wave P^T [q][key]

    const int tid = threadIdx.x;
    const int lane = tid & 63;
    const int w = tid >> 6;
    const int g = lane >> 4, g4 = g * 4, qll = lane & 15;
    const int bh = blockIdx.y;
    const int b_ = bh >> 3, h_ = bh & 7, g_ = h_ & 3;
    const int q0 = blockIdx.x * 64;

    const u16* Qp = qb + (size_t)bh * Sdim * DKc;
    const u16* Kp = kb + (size_t)bh * Sdim * DKc;
    const u16* Vp = vtb + (size_t)bh * DKc * Sdim;
    const u64* mrow = (const u64*)(mpacked + (((size_t)(b_ * 4 + g_) * Sdim * Sdim) >> 5))
                      + (size_t)(q0 + w * 16 + qll) * 16;   // 16 u64 per q-row

    // stage Q tile (64 x 96) into kbuf, pull B-frags (n = q = lane&15)
    #pragma unroll
    for (int i = 0; i < 3; i++) {
        int c = tid + i * 256;
        int row = c / 12, o = (c % 12) * 8;
        *(int4*)&kbuf[row][o] = *(const int4*)(Qp + (size_t)(q0 + row) * DKc + o);
    }
    __syncthreads();
    s16x8 qf[3];
    #pragma unroll
    for (int kk = 0; kk < 3; kk++)
        qf[kk] = *(const s16x8*)&kbuf[w * 16 + qll][kk * 32 + g * 8];
    __syncthreads();

    float m_run = -1e30f, l_run = 0.f;
    f32x4 acc[6];
    #pragma unroll
    for (int n2 = 0; n2 < 6; n2++) acc[n2] = (f32x4){0.f, 0.f, 0.f, 0.f};

    const float sc2 = 0.14724444609f;  // (1/sqrt(96)) * log2(e)

    for (int kt = 0; kt < 16; kt++) {
        const int kb0 = kt * 64;
        __syncthreads();
        // stage K tile [64][96]
        #pragma unroll
        for (int i = 0; i < 3; i++) {
            int c = tid + i * 256;
            int row = c / 12, o = (c % 12) * 8;
            *(int4*)&kbuf[row][o] = *(const int4*)(Kp + (size_t)(kb0 + row) * DKc + o);
        }
        // stage V^T tile [96][64]
        #pragma unroll
        for (int i = 0; i < 3; i++) {
            int c = tid + i * 256;
            int row = c >> 3, o = (c & 7) * 8;
            *(int4*)&vbuf[row][o] = *(const int4*)(Vp + (size_t)row * Sdim + kb0 + o);
        }
        u64 mbits = mrow[kt];   // issue early; used after MFMAs
        __syncthreads();

        // ---- QK^T swapped: D[m=key][n=q]; lane holds q=qll, keys ni*16+g4+r ----
        float s[4][4];  // [ni][r]
        #pragma unroll
        for (int ni = 0; ni < 4; ni++) {
            f32x4 c4 = {0.f, 0.f, 0.f, 0.f};
            #pragma unroll
            for (int kk = 0; kk < 3; kk++) {
                s16x8 kf = *(const s16x8*)&kbuf[ni * 16 + qll][kk * 32 + g * 8];
                c4 = __builtin_amdgcn_mfma_f32_16x16x32_bf16(kf, qf[kk], c4, 0, 0, 0);
            }
            #pragma unroll
            for (int r = 0; r < 4; r++) s[ni][r] = c4[r] * sc2;
        }

        // ---- mask: one u64 per q-row per tile, bit = key offset ----
        #pragma unroll
        for (int ni = 0; ni < 4; ni++) {
            u32 mb = (u32)(mbits >> (ni * 16 + g4));
            #pragma unroll
            for (int r = 0; r < 4; r++)
                if (!((mb >> r) & 1)) s[ni][r] = -1e9f;
        }

        // ---- online softmax, in-register + 2 shfl ----
        float tmax = s[0][0];
        #pragma unroll
        for (int ni = 0; ni < 4; ni++)
            #pragma unroll
            for (int r = 0; r < 4; r++) tmax = fmaxf(tmax, s[ni][r]);
        tmax = fmaxf(tmax, __shfl_xor(tmax, 16));
        tmax = fmaxf(tmax, __shfl_xor(tmax, 32));

        bool rescale = !__all(tmax <= m_run + 8.f);   // defer-max (T13)
        float alpha = 1.f;
        if (rescale) {
            float mn = fmaxf(m_run, tmax);
            alpha = exp2f(m_run - mn);
            m_run = mn;
        }
        float ps = 0.f;
        #pragma unroll
        for (int ni = 0; ni < 4; ni++)
            #pragma unroll
            for (int r = 0; r < 4; r++) {
                float p = exp2f(s[ni][r] - m_run);
                s[ni][r] = p;
                ps += p;
            }
        ps += __shfl_xor(ps, 16);
        ps += __shfl_xor(ps, 32);
        l_run = l_run * alpha + ps;

        if (rescale) {   // broadcast alpha to C-layout rows, rescale O
            float ac[4];
            #pragma unroll
            for (int r = 0; r < 4; r++) ac[r] = __shfl(alpha, g4 + r, 16);
            #pragma unroll
            for (int n2 = 0; n2 < 6; n2++)
                #pragma unroll
                for (int r = 0; r < 4; r++) acc[n2][r] *= ac[r];
        }

        // ---- pack P -> bf16, 4x ds_write_b64 into P^T[q][key] ----
        #pragma unroll
        for (int ni = 0; ni < 4; ni++) {
            u32 lo, hi;
            asm("v_cvt_pk_bf16_f32 %0, %1, %2" : "=v"(lo) : "v"(s[ni][0]), "v"(s[ni][1]));
            asm("v_cvt_pk_bf16_f32 %0, %1, %2" : "=v"(hi) : "v"(s[ni][2]), "v"(s[ni][3]));
            *(uint2*)&pbuf[w][qll][ni * 16 + g4] = make_uint2(lo, hi);
        }
        asm volatile("s_waitcnt lgkmcnt(0)" ::: "memory");  // wave-private P write->read

        // ---- PV: A = P^T[q][key], B = V^T[d'][key] ----
        #pragma unroll
        for (int kk = 0; kk < 2; kk++) {
            s16x8 pf = *(const s16x8*)&pbuf[w][qll][kk * 32 + g * 8];
            #pragma unroll
            for (int n2 = 0; n2 < 6; n2++) {
                s16x8 vf = *(const s16x8*)&vbuf[n2 * 16 + qll][kk * 32 + g * 8];
                acc[n2] = __builtin_amdgcn_mfma_f32_16x16x32_bf16(pf, vf, acc[n2], 0, 0, 0);
            }
        }
    }

    // ---- epilogue: O rows are C-layout (q = g4+r); l_run lives at lane q=qll ----
    float il[4];
    #pragma unroll
    for (int r = 0; r < 4; r++) il[r] = 1.f / __shfl(l_run, g4 + r, 16);
    #pragma unroll
    for (int n2 = 0; n2 < 6; n2++) {
        int dc = h_ * DKc + n2 * 16 + qll;
        #pragma unroll
        for (int r = 0; r < 4; r++) {
            int qrow_c = q0 + w * 16 + g4 + r;
            xb[((size_t)(b_ * Sdim) + qrow_c) * Dd + dc] = f2bf(acc[n2][r] * il[r]);
        }
    }
}

// ---------------------------------------------------------------------------
extern "C" void kernel_launch(void* const* d_in, const int* in_sizes, int n_in,
                              void* d_out, int out_size, void* d_ws, size_t ws_size,
                              hipStream_t stream)
{
    const float* query = (const float*)d_in[0];
    const float* key   = (const float*)d_in[1];
    const float* value = (const float*)d_in[2];
    const int*   mask  = (const int*)d_in[3];
    const float* Wq = (const float*)d_in[4];
    const float* bq = (const float*)d_in[5];
    const float* Wk = (const float*)d_in[6];
    const float* bk = (const float*)d_in[7];
    const float* Wv = (const float*)d_in[8];
    const float* bv = (const float*)d_in[9];
    const float* Wo = (const float*)d_in[10];
    const float* bo = (const float*)d_in[11];
    float* out = (float*)d_out;

    char* ws = (char*)d_ws;
    u16* qb   = (u16*)(ws);                 // 25165824 B  [B,H,S,DK] bf16
    u16* kb   = (u16*)(ws + 25165824);      // 25165824 B
    u16* vtb  = (u16*)(ws + 50331648);      // 25165824 B  [B,H,DK,S] bf16
    u16* xb   = (u16*)(ws + 75497472);      // 25165824 B  [B,S,D] bf16
    u16* wb   = (u16*)(ws + 100663296);     //  4718592 B  4x [768,768] bf16
    unsigned* mp = (unsigned*)(ws + 105381888); // 8388608 B packed mask

    convw_kernel<<<dim3(576, 4), 256, 0, stream>>>(Wq, Wk, Wv, Wo, wb);
    maskpack_kernel<<<dim3(2048), 256, 0, stream>>>(mask, mp);
    gemm_kernel<true><<<dim3(6, 128, 3), 256, 0, stream>>>(
        query, key, value, nullptr, wb, bq, bk, bv, bo, qb, kb, vtb, out, Dd);
    attn_kernel<<<dim3(16, 128), 256, 0, stream>>>(qb, kb, vtb, mp, xb);
    gemm_kernel<false><<<dim3(6, 128, 1), 256, 0, stream>>>(
        nullptr, nullptr, nullptr, xb, wb, bq, bk, bv, bo, qb, kb, vtb, out, Dd);
}

// Round 8
// 783.677 us; speedup vs baseline: 1.0570x; 1.0347x over previous
//
#include <hip/hip_runtime.h>
#include <hip/hip_bf16.h>

typedef unsigned short u16;
typedef unsigned int u32;
typedef unsigned long long u64;
typedef __attribute__((ext_vector_type(4))) float f32x4;
typedef __attribute__((ext_vector_type(8))) short s16x8;

constexpr int Sdim = 1024;
constexpr int Hh   = 8;
constexpr int DKc  = 96;
constexpr int Dd   = 768;
constexpr int Bb   = 16;

static __device__ __forceinline__ u16 f2bf(float f) {
    unsigned u = __builtin_bit_cast(unsigned, f);
    u += 0x7fff + ((u >> 16) & 1);   // round-to-nearest-even
    return (u16)(u >> 16);
}

// async global->LDS, 16B per lane; LDS dest must be wave-uniform base (HW adds lane*16)
static __device__ __forceinline__ void gload_lds16(const u16* g, u16* l) {
    __builtin_amdgcn_global_load_lds(
        (const __attribute__((address_space(1))) u32*)g,
        (__attribute__((address_space(3))) u32*)l, 16, 0, 0);
}

// ---------------------------------------------------------------------------
// Kernel 1: convert the 4 weight matrices (768x768 fp32) to bf16
// ---------------------------------------------------------------------------
__global__ __launch_bounds__(256) void convw_kernel(
    const float* w0, const float* w1, const float* w2, const float* w3, u16* dst)
{
    const float* src = (blockIdx.y == 0) ? w0 : (blockIdx.y == 1) ? w1
                      : (blockIdx.y == 2) ? w2 : w3;
    u16* d = dst + (size_t)blockIdx.y * 589824;
    int i = (blockIdx.x * 256 + threadIdx.x) * 4;
    float4 v = *(const float4*)(src + i);
    ushort4 o;
    o.x = f2bf(v.x); o.y = f2bf(v.y); o.z = f2bf(v.z); o.w = f2bf(v.w);
    *(ushort4*)(d + i) = o;
}

// ---------------------------------------------------------------------------
// Kernel 1b: bit-pack the mask. [B,4,S,S] int32 -> u32 bitfield (8 MiB).
// ---------------------------------------------------------------------------
__global__ __launch_bounds__(256) void maskpack_kernel(const int* mask, unsigned* packed)
{
    const size_t total  = (size_t)Bb * 4 * Sdim * Sdim;   // 67108864
    const size_t stride = (size_t)gridDim.x * 256;
    const int lane = threadIdx.x & 63;
    for (size_t i = (size_t)blockIdx.x * 256 + threadIdx.x; i < total; i += stride) {
        int mv = mask[i];
        u64 bal = __ballot(mv != 0);
        size_t w0 = (i - lane) >> 5;      // u32 index of this wave's span
        if (lane == 0)  packed[w0]     = (unsigned)bal;
        if (lane == 32) packed[w0 + 1] = (unsigned)(bal >> 32);
    }
}

// ---------------------------------------------------------------------------
// Kernel 2/4: GEMM  out = A @ W^T + bias   (K = 768 fixed)
//   1-D grid with XCD panel-group swizzle: j -> XCD j%8 (HW heuristic);
//   the 6 n-tiles of one 128-row A-panel get consecutive slots on ONE XCD,
//   so the panel is fetched into that XCD's L2 once (393 KB fp32 < 4 MB).
//   B (weights) staged via global_load_lds width=16 into linear LDS (m97).
//   QKV: A = fp32 activations, reg-staged with convert; grid 2304.
//   !QKV: A = bf16 xb, async; fp32 out + bias; grid 768.
// ---------------------------------------------------------------------------
template<bool QKV>
__global__ __launch_bounds__(256) void gemm_kernel(
    const float* q_f32, const float* k_f32, const float* v_f32,
    const u16* xb, const u16* wb,
    const float* bq, const float* bk, const float* bv, const float* bo,
    u16* qb, u16* kb, u16* vtb, float* out)
{
    constexpr int LDA = QKV ? 72 : 64;            // pad only the reg-staged A tile
    __shared__ u16 As[128][LDA];
    __shared__ u16 Bs[128][64];

    // ---- XCD panel-group decode ----
    const int j = blockIdx.x;
    const int xcd = j & 7, sIdx = j >> 3;
    const int P = xcd + 8 * (sIdx / 6);   // QKV: [0,384) = z*128+p ; final: [0,128)
    const int nblk = sIdx % 6;
    const int z = QKV ? (P >> 7) : 3;
    const int p = QKV ? (P & 127) : P;

    const float* Af = QKV ? (z == 0 ? q_f32 : z == 1 ? k_f32 : v_f32) : nullptr;
    const u16*   Ab = QKV ? nullptr : xb;
    const u16*   W  = wb + (size_t)z * 589824;
    const float* bias = QKV ? (z == 0 ? bq : z == 1 ? bk : bv) : bo;

    const int tid = threadIdx.x;
    const int lane = tid & 63;
    const int w = tid >> 6;
    const int wr = (w >> 1) * 64, wc = (w & 1) * 64;
    const int m0 = p * 128, n0 = nblk * 128;

    f32x4 acc[4][4] = {};

    for (int k0 = 0; k0 < 768; k0 += 64) {
        __syncthreads();
        // ---- B tile async: 128x64 bf16 = 1024 16B-chunks, 16 wave-issues ----
        #pragma unroll
        for (int i = 0; i < 4; i++) {
            int c = (w * 4 + i) * 64 + lane;
            int row = c >> 3, col = (c & 7) * 8;
            gload_lds16(W + (size_t)(n0 + row) * 768 + k0 + col,
                        ((u16*)Bs) + (size_t)(w * 4 + i) * 512);
        }
        // ---- A tile ----
        if constexpr (QKV) {
            // fp32 source (L2-hot via swizzle): reg-stage + convert
            #pragma unroll
            for (int i = 0; i < 8; i++) {
                int c = tid + i * 256;
                int row = c >> 4, o4 = (c & 15) * 4;
                float4 v = *(const float4*)(Af + (size_t)(m0 + row) * 768 + k0 + o4);
                ushort4 o;
                o.x = f2bf(v.x); o.y = f2bf(v.y); o.z = f2bf(v.z); o.w = f2bf(v.w);
                *(ushort4*)&As[row][o4] = o;
            }
        } else {
            #pragma unroll
            for (int i = 0; i < 4; i++) {
                int c = (w * 4 + i) * 64 + lane;
                int row = c >> 3, col = (c & 7) * 8;
                gload_lds16(Ab + (size_t)(m0 + row) * 768 + k0 + col,
                            ((u16*)As) + (size_t)(w * 4 + i) * 512);
            }
        }
        __syncthreads();   // drains vmcnt (incl. global_load_lds) + lgkm
        // ---- compute ----
        #pragma unroll
        for (int kk = 0; kk < 2; kk++) {
            s16x8 a[4], b[4];
            #pragma unroll
            for (int mi = 0; mi < 4; mi++)
                a[mi] = *(const s16x8*)&As[wr + mi * 16 + (lane & 15)][kk * 32 + (lane >> 4) * 8];
            #pragma unroll
            for (int ni = 0; ni < 4; ni++)
                b[ni] = *(const s16x8*)&Bs[wc + ni * 16 + (lane & 15)][kk * 32 + (lane >> 4) * 8];
            #pragma unroll
            for (int mi = 0; mi < 4; mi++)
                #pragma unroll
                for (int ni = 0; ni < 4; ni++)
                    acc[mi][ni] = __builtin_amdgcn_mfma_f32_16x16x32_bf16(
                        a[mi], b[ni], acc[mi][ni], 0, 0, 0);
        }
    }

    // ---- epilogue ----
    #pragma unroll
    for (int mi = 0; mi < 4; mi++) {
        #pragma unroll
        for (int ni = 0; ni < 4; ni++) {
            int nc = n0 + wc + ni * 16 + (lane & 15);
            int mr0 = m0 + wr + mi * 16 + (lane >> 4) * 4;
            float bvv = bias[nc];
            float vals[4];
            #pragma unroll
            for (int r = 0; r < 4; r++) vals[r] = acc[mi][ni][r] + bvv;

            if constexpr (!QKV) {
                #pragma unroll
                for (int r = 0; r < 4; r++)
                    out[(size_t)(mr0 + r) * Dd + nc] = vals[r];
            } else {
                int b_ = mr0 >> 10, s_ = mr0 & 1023;   // r=0..3 stays in-batch (4-aligned)
                int h_ = nc / DKc, dk = nc - h_ * DKc;
                if (z == 2) {
                    ushort4 o;
                    o.x = f2bf(vals[0]); o.y = f2bf(vals[1]);
                    o.z = f2bf(vals[2]); o.w = f2bf(vals[3]);
                    *(ushort4*)&vtb[((size_t)(b_ * Hh + h_) * DKc + dk) * Sdim + s_] = o;
                } else {
                    u16* dst = (z == 0) ? qb : kb;
                    #pragma unroll
                    for (int r = 0; r < 4; r++)
                        dst[((size_t)(b_ * Hh + h_) * Sdim + (s_ + r)) * DKc + dk] = f2bf(vals[r]);
                }
            }
        }
    }
}

// ---------------------------------------------------------------------------
// Kernel 3: flash attention, SWAPPED QK^T (S^T = K x Q^T) so each lane owns
// one q-row's 16 scores per 64-key tile: in-register reduce + 2 shfl_xor.
// exp2-domain softmax, defer-max (THR=8), P packed via v_cvt_pk_bf16_f32.
// 1-D grid 2048, XCD swizzle: the 16 q-blocks of one (b,h) share an XCD so
// K/V (384 KB bf16) are fetched into that XCD's L2 once.
// block 256 (4 waves, wave w: q-rows [w*16, w*16+16))
// ---------------------------------------------------------------------------
__global__ __launch_bounds__(256) void attn_kernel(
    const u16* qb, const u16* kb, const u16* vtb, const unsigned* mpacked, u16* xb)
{
    __shared__ u16 kbuf[64][104];    // K tile [key][d] (also Q staging); 2-way-free pad
    __shared__ u16 vbuf[96][72];     // V^T tile [d'][key]
    __shared__ u16 pbuf[4][16][72];  // per-wave P^T [q][key]

    const int tid = threadIdx.x;
    const int lane = tid & 63;
    const int w = tid >> 6;
    const int g = lane >> 4, g4 = g * 4, qll = lane & 15;
    // ---- XCD swizzle decode: bh = (j&7) + 8*((j>>3)>>4), q-block = (j>>3)&15 ----
    const int j = blockIdx.x;
    const int bh = (j & 7) + 8 * (j >> 7);
    const int b_ = bh >> 3, h_ = bh & 7, g_ = h_ & 3;
    const int q0 = ((j >> 3) & 15) * 64;

    const u16* Qp = qb + (size_t)bh * Sdim * DKc;
    const u16* Kp = kb + (size_t)bh * Sdim * DKc;
    const u16* Vp = vtb + (size_t)bh * DKc * Sdim;
    const u64* mrow = (const u64*)(mpacked + (((size_t)(b_ * 4 + g_) * Sdim * Sdim) >> 5))
                      + (size_t)(q0 + w * 16 + qll) * 16;   // 16 u64 per q-row

    // stage Q tile (64 x 96) into kbuf, pull B-frags (n = q = lane&15)
    #pragma unroll
    for (int i = 0; i < 3; i++) {
        int c = tid + i * 256;
        int row = c / 12, o = (c % 12) * 8;
        *(int4*)&kbuf[row][o] = *(const int4*)(Qp + (size_t)(q0 + row) * DKc + o);
    }
    __syncthreads();
    s16x8 qf[3];
    #pragma unroll
    for (int kk = 0; kk < 3; kk++)
        qf[kk] = *(const s16x8*)&kbuf[w * 16 + qll][kk * 32 + g * 8];
    __syncthreads();

    float m_run = -1e30f, l_run = 0.f;
    f32x4 acc[6];
    #pragma unroll
    for (int n2 = 0; n2 < 6; n2++) acc[n2] = (f32x4){0.f, 0.f, 0.f, 0.f};

    const float sc2 = 0.14724444609f;  // (1/sqrt(96)) * log2(e)

    for (int kt = 0; kt < 16; kt++) {
        const int kb0 = kt * 64;
        __syncthreads();
        // stage K tile [64][96]
        #pragma unroll
        for (int i = 0; i < 3; i++) {
            int c = tid + i * 256;
            int row = c / 12, o = (c % 12) * 8;
            *(int4*)&kbuf[row][o] = *(const int4*)(Kp + (size_t)(kb0 + row) * DKc + o);
        }
        // stage V^T tile [96][64]
        #pragma unroll
        for (int i = 0; i < 3; i++) {
            int c = tid + i * 256;
            int row = c >> 3, o = (c & 7) * 8;
            *(int4*)&vbuf[row][o] = *(const int4*)(Vp + (size_t)row * Sdim + kb0 + o);
        }
        u64 mbits = mrow[kt];   // issue early; used after MFMAs
        __syncthreads();

        // ---- QK^T swapped: D[m=key][n=q]; lane holds q=qll, keys ni*16+g4+r ----
        float s[4][4];  // [ni][r]
        #pragma unroll
        for (int ni = 0; ni < 4; ni++) {
            f32x4 c4 = {0.f, 0.f, 0.f, 0.f};
            #pragma unroll
            for (int kk = 0; kk < 3; kk++) {
                s16x8 kf = *(const s16x8*)&kbuf[ni * 16 + qll][kk * 32 + g * 8];
                c4 = __builtin_amdgcn_mfma_f32_16x16x32_bf16(kf, qf[kk], c4, 0, 0, 0);
            }
            #pragma unroll
            for (int r = 0; r < 4; r++) s[ni][r] = c4[r] * sc2;
        }

        // ---- mask: one u64 per q-row per tile, bit = key offset ----
        #pragma unroll
        for (int ni = 0; ni < 4; ni++) {
            u32 mb = (u32)(mbits >> (ni * 16 + g4));
            #pragma unroll
            for (int r = 0; r < 4; r++)
                if (!((mb >> r) & 1)) s[ni][r] = -1e9f;
        }

        // ---- online softmax, in-register + 2 shfl ----
        float tmax = s[0][0];
        #pragma unroll
        for (int ni = 0; ni < 4; ni++)
            #pragma unroll
            for (int r = 0; r < 4; r++) tmax = fmaxf(tmax, s[ni][r]);
        tmax = fmaxf(tmax, __shfl_xor(tmax, 16));
        tmax = fmaxf(tmax, __shfl_xor(tmax, 32));

        bool rescale = !__all(tmax <= m_run + 8.f);   // defer-max (T13)
        float alpha = 1.f;
        if (rescale) {
            float mn = fmaxf(m_run, tmax);
            alpha = exp2f(m_run - mn);
            m_run = mn;
        }
        float ps = 0.f;
        #pragma unroll
        for (int ni = 0; ni < 4; ni++)
            #pragma unroll
            for (int r = 0; r < 4; r++) {
                float p = exp2f(s[ni][r] - m_run);
                s[ni][r] = p;
                ps += p;
            }
        ps += __shfl_xor(ps, 16);
        ps += __shfl_xor(ps, 32);
        l_run = l_run * alpha + ps;

        if (rescale) {   // broadcast alpha to C-layout rows, rescale O
            float ac[4];
            #pragma unroll
            for (int r = 0; r < 4; r++) ac[r] = __shfl(alpha, g4 + r, 16);
            #pragma unroll
            for (int n2 = 0; n2 < 6; n2++)
                #pragma unroll
                for (int r = 0; r < 4; r++) acc[n2][r] *= ac[r];
        }

        // ---- pack P -> bf16, 4x ds_write_b64 into P^T[q][key] ----
        #pragma unroll
        for (int ni = 0; ni < 4; ni++) {
            u32 lo, hi;
            asm("v_cvt_pk_bf16_f32 %0, %1, %2" : "=v"(lo) : "v"(s[ni][0]), "v"(s[ni][1]));
            asm("v_cvt_pk_bf16_f32 %0, %1, %2" : "=v"(hi) : "v"(s[ni][2]), "v"(s[ni][3]));
            *(uint2*)&pbuf[w][qll][ni * 16 + g4] = make_uint2(lo, hi);
        }
        asm volatile("s_waitcnt lgkmcnt(0)" ::: "memory");  // wave-private P write->read

        // ---- PV: A = P^T[q][key], B = V^T[d'][key] ----
        #pragma unroll
        for (int kk = 0; kk < 2; kk++) {
            s16x8 pf = *(const s16x8*)&pbuf[w][qll][kk * 32 + g * 8];
            #pragma unroll
            for (int n2 = 0; n2 < 6; n2++) {
                s16x8 vf = *(const s16x8*)&vbuf[n2 * 16 + qll][kk * 32 + g * 8];
                acc[n2] = __builtin_amdgcn_mfma_f32_16x16x32_bf16(pf, vf, acc[n2], 0, 0, 0);
            }
        }
    }

    // ---- epilogue: O rows are C-layout (q = g4+r); l_run lives at lane q=qll ----
    float il[4];
    #pragma unroll
    for (int r = 0; r < 4; r++) il[r] = 1.f / __shfl(l_run, g4 + r, 16);
    #pragma unroll
    for (int n2 = 0; n2 < 6; n2++) {
        int dc = h_ * DKc + n2 * 16 + qll;
        #pragma unroll
        for (int r = 0; r < 4; r++) {
            int qrow_c = q0 + w * 16 + g4 + r;
            xb[((size_t)(b_ * Sdim) + qrow_c) * Dd + dc] = f2bf(acc[n2][r] * il[r]);
        }
    }
}

// ---------------------------------------------------------------------------
extern "C" void kernel_launch(void* const* d_in, const int* in_sizes, int n_in,
                              void* d_out, int out_size, void* d_ws, size_t ws_size,
                              hipStream_t stream)
{
    const float* query = (const float*)d_in[0];
    const float* key   = (const float*)d_in[1];
    const float* value = (const float*)d_in[2];
    const int*   mask  = (const int*)d_in[3];
    const float* Wq = (const float*)d_in[4];
    const float* bq = (const float*)d_in[5];
    const float* Wk = (const float*)d_in[6];
    const float* bk = (const float*)d_in[7];
    const float* Wv = (const float*)d_in[8];
    const float* bv = (const float*)d_in[9];
    const float* Wo = (const float*)d_in[10];
    const float* bo = (const float*)d_in[11];
    float* out = (float*)d_out;

    char* ws = (char*)d_ws;
    u16* qb   = (u16*)(ws);                 // 25165824 B  [B,H,S,DK] bf16
    u16* kb   = (u16*)(ws + 25165824);      // 25165824 B
    u16* vtb  = (u16*)(ws + 50331648);      // 25165824 B  [B,H,DK,S] bf16
    u16* xb   = (u16*)(ws + 75497472);      // 25165824 B  [B,S,D] bf16
    u16* wb   = (u16*)(ws + 100663296);     //  4718592 B  4x [768,768] bf16
    unsigned* mp = (unsigned*)(ws + 105381888); // 8388608 B packed mask

    convw_kernel<<<dim3(576, 4), 256, 0, stream>>>(Wq, Wk, Wv, Wo, wb);
    maskpack_kernel<<<dim3(2048), 256, 0, stream>>>(mask, mp);
    gemm_kernel<true><<<dim3(2304), 256, 0, stream>>>(
        query, key, value, nullptr, wb, bq, bk, bv, bo, qb, kb, vtb, out);
    attn_kernel<<<dim3(2048), 256, 0, stream>>>(qb, kb, vtb, mp, xb);
    gemm_kernel<false><<<dim3(768), 256, 0, stream>>>(
        nullptr, nullptr, nullptr, xb, wb, bq, bk, bv, bo, qb, kb, vtb, out);
}